// Round 1
// baseline (208.613 us; speedup 1.0000x reference)
//
#include <hip/hip_runtime.h>
#include <hip/hip_bf16.h>
#include <cstdint>

// Problem constants
#define CIN   256
#define COUT  256
#define NB    8
#define NT    16
#define NH    28
#define NW    28
#define HP    30   // padded H
#define WP    30   // padded W

// ws layout
#define XM_ELEMS   ((size_t)NB * NT * HP * WP * CIN)       // 29,491,200 bf16
#define XM_BYTES   (XM_ELEMS * 2)                          // 58,982,400
#define WB_ELEMS   ((size_t)9 * COUT * CIN)                // 589,824 bf16

typedef __bf16 bf16x8 __attribute__((ext_vector_type(8)));
typedef float  f32x4  __attribute__((ext_vector_type(4)));

static __device__ __forceinline__ unsigned short f2bf(float f) {
    __hip_bfloat16 h = __float2bfloat16(f);
    return __builtin_bit_cast(unsigned short, h);
}

// ---------------------------------------------------------------------------
// Pass 1: xm[b][t][hp][wp][ci] = bf16(x[b][ci][t][h][w] * alpha[b][ci][t])
// Padded borders written as zero. grid = (B*T*30), block = 256 (ci)
// ---------------------------------------------------------------------------
__global__ void modulate_kernel(const float* __restrict__ x,
                                const float* __restrict__ alpha,
                                unsigned short* __restrict__ xm) {
    const int ci = threadIdx.x;
    const int blk = blockIdx.x;            // bt*30 + hp
    const int hp = blk % 30;
    const int bt = blk / 30;               // b*16 + t
    unsigned short* row = xm + (size_t)(bt * 900 + hp * 30) * 256;
    if (hp == 0 || hp == 29) {
        #pragma unroll
        for (int wp = 0; wp < 30; ++wp) row[wp * 256 + ci] = 0;
        return;
    }
    const int t = bt & 15, b = bt >> 4;
    const int h = hp - 1;
    const float a = alpha[(b * CIN + ci) * NT + t];
    const float* xrow = x + ((size_t)((b * CIN + ci) * NT + t) * NH + h) * NW;
    row[ci] = 0;
    row[29 * 256 + ci] = 0;
    const float4* xv = (const float4*)xrow;   // 28 floats/row start 112B-aligned -> 16B ok
    #pragma unroll
    for (int q = 0; q < 7; ++q) {
        float4 v = xv[q];
        row[(q * 4 + 1) * 256 + ci] = f2bf(v.x * a);
        row[(q * 4 + 2) * 256 + ci] = f2bf(v.y * a);
        row[(q * 4 + 3) * 256 + ci] = f2bf(v.z * a);
        row[(q * 4 + 4) * 256 + ci] = f2bf(v.w * a);
    }
}

// ---------------------------------------------------------------------------
// Pass 2: wB[tap][co][ci] = bf16(weight[co][ci][tap]); grid = 9*256, block=256
// ---------------------------------------------------------------------------
__global__ void repack_w_kernel(const float* __restrict__ w,
                                unsigned short* __restrict__ wB) {
    const int ci = threadIdx.x;
    const int tap = blockIdx.x >> 8;
    const int co  = blockIdx.x & 255;
    wB[((tap * 256 + co) * 256) + ci] = f2bf(w[(co * 256 + ci) * 9 + tap]);
}

// ---------------------------------------------------------------------------
// Pass 3: implicit GEMM. C[co][n] = sum_{tap,ci} wB[tap][co][ci] * xm[...]
// 128x128 tile, BK=64, 4 waves, mfma_f32_16x16x32_bf16.
// LDS tiles [row][k] with XOR swizzle byte ^= ((row&7)<<4); staging via
// global_load_lds(16B) with pre-swizzled per-lane global source.
// grid = (784, 2), block = 256.
// ---------------------------------------------------------------------------
__global__ __launch_bounds__(256, 2) void conv_gemm_kernel(
    const unsigned short* __restrict__ xm,
    const unsigned short* __restrict__ wB,
    float* __restrict__ out) {
    __shared__ unsigned short As[128 * 64];
    __shared__ unsigned short Bs[128 * 64];

    const int tid  = threadIdx.x;
    const int wave = tid >> 6;
    const int lane = tid & 63;
    const int n0   = blockIdx.x * 128;   // spatial tile base
    const int co0  = blockIdx.y * 128;   // cout tile base

    // staging geometry: chunk c = wave*4+j covers rows c*8..c*8+7; lane writes
    // LDS linear off = c*1024 + lane*16. Inverse-swizzled global k offset:
    const int lm8    = lane >> 3;            // row-within-chunk
    const int ll     = lane & 7;             // 16B slot within row
    const int ci_off = 8 * (ll ^ lm8);       // pre-swizzled source k

    const unsigned short* a_src[4];
    const unsigned short* b_src[4];
    #pragma unroll
    for (int j = 0; j < 4; ++j) {
        const int c = wave * 4 + j;
        const int m = c * 8 + lm8;           // 0..127
        a_src[j] = wB + (co0 + m) * 256 + ci_off;
        const int n  = n0 + m;               // flat spatial (b,t,h,w)
        const int w  = n % 28;
        const int h  = (n / 28) % 28;
        const int bt = n / 784;
        // padded center address (h+1, w+1)
        b_src[j] = xm + ((bt * 30 + h + 1) * 30 + (w + 1)) * 256 + ci_off;
    }

    // fragment read: byte = row*128 + (((lane>>4)*16) ^ ((lane&7)<<4)) ^ (kk<<6)
    const int l15     = lane & 15;
    const int frag_sw = ((lane >> 4) * 16) ^ ((lane & 7) << 4);
    const int wm = wave >> 1, wn = wave & 1;   // 2x2 wave grid, 64x64 each

    f32x4 acc[4][4];
    #pragma unroll
    for (int i = 0; i < 4; ++i)
        #pragma unroll
        for (int j = 0; j < 4; ++j)
            acc[i][j] = f32x4{0.f, 0.f, 0.f, 0.f};

    for (int tap = 0; tap < 9; ++tap) {
        const int kh = tap / 3, kw = tap % 3;
        const int b_tap = ((kh - 1) * 30 + (kw - 1)) * 256;   // may be negative
        const int a_tap = tap * 65536;
        #pragma unroll 1
        for (int ci0 = 0; ci0 < 256; ci0 += 64) {
            #pragma unroll
            for (int j = 0; j < 4; ++j) {
                const int c = wave * 4 + j;
                __builtin_amdgcn_global_load_lds(
                    (const __attribute__((address_space(1))) void*)(a_src[j] + a_tap + ci0),
                    (__attribute__((address_space(3))) void*)(&As[c * 512]),
                    16, 0, 0);
                __builtin_amdgcn_global_load_lds(
                    (const __attribute__((address_space(1))) void*)(b_src[j] + b_tap + ci0),
                    (__attribute__((address_space(3))) void*)(&Bs[c * 512]),
                    16, 0, 0);
            }
            __syncthreads();
            #pragma unroll
            for (int kk = 0; kk < 2; ++kk) {
                const int sw = frag_sw ^ (kk << 6);
                bf16x8 af[4], bq[4];
                #pragma unroll
                for (int i = 0; i < 4; ++i)
                    af[i] = *(const bf16x8*)((const char*)As +
                            ((wm * 64 + i * 16 + l15) * 128 + sw));
                #pragma unroll
                for (int j = 0; j < 4; ++j)
                    bq[j] = *(const bf16x8*)((const char*)Bs +
                            ((wn * 64 + j * 16 + l15) * 128 + sw));
                #pragma unroll
                for (int i = 0; i < 4; ++i)
                    #pragma unroll
                    for (int j = 0; j < 4; ++j)
                        acc[i][j] = __builtin_amdgcn_mfma_f32_16x16x32_bf16(
                            af[i], bq[j], acc[i][j], 0, 0, 0);
            }
            __syncthreads();
        }
    }

    // epilogue: C/D layout col=lane&15 (n), row=(lane>>4)*4+reg (co)
    const int row4 = (lane >> 4) * 4;
    #pragma unroll
    for (int j = 0; j < 4; ++j) {
        const int n  = n0 + wn * 64 + j * 16 + l15;
        const int r2 = n % 784;              // h*28+w
        const int bt = n / 784;
        const int b = bt >> 4, t = bt & 15;
        #pragma unroll
        for (int i = 0; i < 4; ++i) {
            const int co = co0 + wm * 64 + i * 16 + row4;
            float* o = out + (((size_t)(b * 256 + co) * 16 + t) * 784) + r2;
            f32x4 v = acc[i][j];
            o[0]             = v[0];
            o[12544]         = v[1];   // +1 co  (T*H*W)
            o[2 * 12544]     = v[2];
            o[3 * 12544]     = v[3];
        }
    }
}

// ---------------------------------------------------------------------------
extern "C" void kernel_launch(void* const* d_in, const int* in_sizes, int n_in,
                              void* d_out, int out_size, void* d_ws, size_t ws_size,
                              hipStream_t stream) {
    const float* x      = (const float*)d_in[0];
    const float* alpha  = (const float*)d_in[1];
    const float* weight = (const float*)d_in[2];
    float* out = (float*)d_out;

    unsigned short* xm = (unsigned short*)d_ws;
    unsigned short* wB = (unsigned short*)((char*)d_ws + XM_BYTES);

    modulate_kernel<<<dim3(NB * NT * HP), dim3(256), 0, stream>>>(x, alpha, xm);
    repack_w_kernel<<<dim3(9 * 256), dim3(256), 0, stream>>>(weight, wB);
    conv_gemm_kernel<<<dim3(784, 2), dim3(256), 0, stream>>>(xm, wB, out);
}

// Round 2
// 171.615 us; speedup vs baseline: 1.2156x; 1.2156x over previous
//
#include <hip/hip_runtime.h>
#include <hip/hip_bf16.h>
#include <cstdint>

// Problem constants
#define CIN   256
#define COUT  256
#define NB    8
#define NT    16
#define NH    28
#define NW    28
#define HP    30
#define WP    30

#define XM_ELEMS   ((size_t)NB * NT * HP * WP * CIN)   // 29,491,200 bf16
#define XM_BYTES   (XM_ELEMS * 2)

typedef __bf16 bf16x8 __attribute__((ext_vector_type(8)));
typedef float  f32x4  __attribute__((ext_vector_type(4)));

#define AS1 __attribute__((address_space(1)))
#define AS3 __attribute__((address_space(3)))

static __device__ __forceinline__ unsigned short f2bf(float f) {
    __hip_bfloat16 h = __float2bfloat16(f);
    return __builtin_bit_cast(unsigned short, h);
}

// ---------------------------------------------------------------------------
// Pass 1: xm[b][t][hp][wp][ci] = bf16(x[b][ci][t][h][w] * alpha[b][ci][t])
// ---------------------------------------------------------------------------
__global__ void modulate_kernel(const float* __restrict__ x,
                                const float* __restrict__ alpha,
                                unsigned short* __restrict__ xm) {
    const int ci = threadIdx.x;
    const int blk = blockIdx.x;
    const int hp = blk % 30;
    const int bt = blk / 30;
    unsigned short* row = xm + (size_t)(bt * 900 + hp * 30) * 256;
    if (hp == 0 || hp == 29) {
        #pragma unroll
        for (int wp = 0; wp < 30; ++wp) row[wp * 256 + ci] = 0;
        return;
    }
    const int t = bt & 15, b = bt >> 4;
    const int h = hp - 1;
    const float a = alpha[(b * CIN + ci) * NT + t];
    const float* xrow = x + ((size_t)((b * CIN + ci) * NT + t) * NH + h) * NW;
    row[ci] = 0;
    row[29 * 256 + ci] = 0;
    const float4* xv = (const float4*)xrow;
    #pragma unroll
    for (int q = 0; q < 7; ++q) {
        float4 v = xv[q];
        row[(q * 4 + 1) * 256 + ci] = f2bf(v.x * a);
        row[(q * 4 + 2) * 256 + ci] = f2bf(v.y * a);
        row[(q * 4 + 3) * 256 + ci] = f2bf(v.z * a);
        row[(q * 4 + 4) * 256 + ci] = f2bf(v.w * a);
    }
}

// ---------------------------------------------------------------------------
// Pass 2: wB[tap][co][ci] = bf16(weight[co][ci][tap])
// ---------------------------------------------------------------------------
__global__ void repack_w_kernel(const float* __restrict__ w,
                                unsigned short* __restrict__ wB) {
    const int ci = threadIdx.x;
    const int tap = blockIdx.x >> 8;
    const int co  = blockIdx.x & 255;
    wB[((tap * 256 + co) * 256) + ci] = f2bf(w[(co * 256 + ci) * 9 + tap]);
}

// ---------------------------------------------------------------------------
// Pass 3: 256x256 implicit GEMM, 8-phase schedule, counted vmcnt.
// M=256 (co), N=256-tile (spatial), K=2304 = 36 tiles of BK=64 (tap-major).
// 8 waves (2M x 4N), LDS 128KB = 2 dbuf x (A 32KB + B 32KB), XOR-swizzled.
// grid = 392, block = 512.
// ---------------------------------------------------------------------------

// stage: chunk = half*16 + 2*wave + j (8 rows); LDS dest linear; global src
// pre-swizzled so that swizzled ds_read sees byte ^ ((row&7)<<4).
#define STAGE_A(buf, half, off) do {                                          \
    __builtin_amdgcn_global_load_lds(                                         \
        (const AS1 void*)(aPtr##half##0 + (off)),                             \
        (AS3 void*)(lds + (buf)*32768 + ((half)*16 + 2*wave + 0)*512 + lane*8), \
        16, 0, 0);                                                            \
    __builtin_amdgcn_global_load_lds(                                         \
        (const AS1 void*)(aPtr##half##1 + (off)),                             \
        (AS3 void*)(lds + (buf)*32768 + ((half)*16 + 2*wave + 1)*512 + lane*8), \
        16, 0, 0);                                                            \
} while (0)

#define STAGE_B(buf, half, off) do {                                          \
    __builtin_amdgcn_global_load_lds(                                         \
        (const AS1 void*)(bPtr##half##0 + (off)),                             \
        (AS3 void*)(lds + (buf)*32768 + 16384 + ((half)*16 + 2*wave + 0)*512 + lane*8), \
        16, 0, 0);                                                            \
    __builtin_amdgcn_global_load_lds(                                         \
        (const AS1 void*)(bPtr##half##1 + (off)),                             \
        (AS3 void*)(lds + (buf)*32768 + 16384 + ((half)*16 + 2*wave + 1)*512 + lane*8), \
        16, 0, 0);                                                            \
} while (0)

#define READ_A(dst, buf, mlo) do {                                            \
    _Pragma("unroll") for (int m_ = 0; m_ < 4; ++m_)                          \
    _Pragma("unroll") for (int kk_ = 0; kk_ < 2; ++kk_)                       \
        dst[m_][kk_] = *(const bf16x8*)(ldsc + (buf)*65536 + aRB[kk_] + ((mlo)+m_)*2048); \
} while (0)

#define READ_B(dst, buf, nlo) do {                                            \
    _Pragma("unroll") for (int n_ = 0; n_ < 2; ++n_)                          \
    _Pragma("unroll") for (int kk_ = 0; kk_ < 2; ++kk_)                       \
        dst[n_][kk_] = *(const bf16x8*)(ldsc + (buf)*65536 + bRB[kk_] + ((nlo)+n_)*2048); \
} while (0)

#define MFMA_Q(mlo, nlo, FA, FB) do {                                         \
    _Pragma("unroll") for (int m_ = 0; m_ < 4; ++m_)                          \
    _Pragma("unroll") for (int n_ = 0; n_ < 2; ++n_)                          \
    _Pragma("unroll") for (int kk_ = 0; kk_ < 2; ++kk_)                       \
        acc[(mlo)+m_][(nlo)+n_] = __builtin_amdgcn_mfma_f32_16x16x32_bf16(    \
            FA[m_][kk_], FB[n_][kk_], acc[(mlo)+m_][(nlo)+n_], 0, 0, 0);      \
} while (0)

#define BAR()   __builtin_amdgcn_s_barrier()
#define LGKM0() asm volatile("s_waitcnt lgkmcnt(0)")
#define VMW(N)  asm volatile("s_waitcnt vmcnt(" #N ")" ::: "memory")
#define PRIO(x) __builtin_amdgcn_s_setprio(x)

__global__ __launch_bounds__(512, 2) void conv_gemm_kernel(
    const unsigned short* __restrict__ xm,
    const unsigned short* __restrict__ wB,
    float* __restrict__ out) {
    __shared__ unsigned short lds[65536];   // 128 KB

    const int tid  = threadIdx.x;
    const int wave = tid >> 6;
    const int lane = tid & 63;
    const int n0   = blockIdx.x * 256;
    const int wr   = wave >> 2;            // 0..1 M-half
    const int wn   = wave & 3;             // 0..3 N-quarter
    const int l15  = lane & 15;

    // ---- staging source addresses (pre-swizzled k offset) ----
    const int swz8 = 8 * ((lane & 7) ^ (lane >> 3));
    const unsigned short* aPtr00 = wB + ((2*wave + 0)*8       + (lane>>3))*256 + swz8;
    const unsigned short* aPtr01 = wB + ((2*wave + 1)*8       + (lane>>3))*256 + swz8;
    const unsigned short* aPtr10 = wB + ((2*wave + 0)*8 + 128 + (lane>>3))*256 + swz8;
    const unsigned short* aPtr11 = wB + ((2*wave + 1)*8 + 128 + (lane>>3))*256 + swz8;

    auto bcenter = [&](int rowl) -> const unsigned short* {
        int n = n0 + rowl;
        int w_ = n % 28, h_ = (n / 28) % 28, bt = n / 784;
        return xm + (size_t)((bt*30 + h_ + 1)*30 + (w_ + 1))*256 + swz8;
    };
    const unsigned short* bPtr00 = bcenter((2*wave + 0)*8       + (lane>>3));
    const unsigned short* bPtr01 = bcenter((2*wave + 1)*8       + (lane>>3));
    const unsigned short* bPtr10 = bcenter((2*wave + 0)*8 + 128 + (lane>>3));
    const unsigned short* bPtr11 = bcenter((2*wave + 1)*8 + 128 + (lane>>3));

    // ---- fragment read bases (byte offsets into a buffer) ----
    const char* ldsc = (const char*)lds;
    const int frag_sw = ((lane >> 4) * 16) ^ ((lane & 7) << 4);
    const int aRB[2] = { (wr*128 + l15)*128 + frag_sw,
                         (wr*128 + l15)*128 + (frag_sw ^ 64) };
    const int bRB[2] = { 32768 + (wn*64 + l15)*128 + frag_sw,
                         32768 + (wn*64 + l15)*128 + (frag_sw ^ 64) };

    f32x4 acc[8][4];
    #pragma unroll
    for (int i = 0; i < 8; ++i)
        #pragma unroll
        for (int j = 0; j < 4; ++j) acc[i][j] = f32x4{0.f,0.f,0.f,0.f};

    bf16x8 fa0[4][2], fa1[4][2], fb0[2][2], fb1[2][2];

    // ---- prologue: kt0=0 -> buf0 (all), kt1=1 -> buf1.B0/B1 ----
    // tap 0 B offset = ((0/3)-1)*7680 + ((0%3)-1)*256 = -7936
    STAGE_B(0, 0, -7936);       // B0(kt0)
    STAGE_B(0, 1, -7936);       // B1(kt0)
    STAGE_A(0, 0, 0);           // A0(kt0)
    STAGE_A(0, 1, 0);           // A1(kt0)
    STAGE_B(1, 0, -7936 + 64);  // B0(kt1)
    STAGE_B(1, 1, -7936 + 64);  // B1(kt1)
    VMW(4);
    BAR();

    #pragma unroll 1
    for (int it = 0; it < 17; ++it) {
        const int kt1 = 2*it + 1;
        const int ka  = 2*it + 2;
        const int kb  = 2*it + 3;
        const int offA_k1 = (kt1 >> 2)*65536 + (kt1 & 3)*64;
        const int tA = ka >> 2, tB = kb >> 2;
        const int offA_ka = tA*65536 + (ka & 3)*64;
        const int offB_ka = ((tA/3) - 1)*7680 + ((tA%3) - 1)*256 + (ka & 3)*64;
        const int offB_kb = ((tB/3) - 1)*7680 + ((tB%3) - 1)*256 + (kb & 3)*64;

        // P1: compute kt0.Q0 ; stage buf1.A0(kt1)
        READ_A(fa0, 0, 0); READ_B(fb0, 0, 0);
        STAGE_A(1, 0, offA_k1);
        BAR(); LGKM0(); PRIO(1); MFMA_Q(0, 0, fa0, fb0); PRIO(0); BAR();
        // P2: kt0.Q1 ; stage buf1.A1(kt1)
        READ_B(fb1, 0, 2);
        STAGE_A(1, 1, offA_k1);
        BAR(); LGKM0(); PRIO(1); MFMA_Q(0, 2, fa0, fb1); PRIO(0); BAR();
        // P3: kt0.Q2 ; stage buf0.B0(ka)
        READ_A(fa1, 0, 4);
        STAGE_B(0, 0, offB_ka);
        BAR(); LGKM0(); PRIO(1); MFMA_Q(4, 2, fa1, fb1); PRIO(0); BAR();
        // P4: kt0.Q3 ; stage buf0.B1(ka) ; counted wait
        STAGE_B(0, 1, offB_ka);
        VMW(4);
        BAR(); PRIO(1); MFMA_Q(4, 0, fa1, fb0); PRIO(0); BAR();
        // P5: kt1.Q0 ; stage buf0.A0(ka)
        READ_A(fa0, 1, 0); READ_B(fb0, 1, 0);
        STAGE_A(0, 0, offA_ka);
        BAR(); LGKM0(); PRIO(1); MFMA_Q(0, 0, fa0, fb0); PRIO(0); BAR();
        // P6: kt1.Q1 ; stage buf0.A1(ka)
        READ_B(fb1, 1, 2);
        STAGE_A(0, 1, offA_ka);
        BAR(); LGKM0(); PRIO(1); MFMA_Q(0, 2, fa0, fb1); PRIO(0); BAR();
        // P7: kt1.Q2 ; stage buf1.B0(kb)
        READ_A(fa1, 1, 4);
        STAGE_B(1, 0, offB_kb);
        BAR(); LGKM0(); PRIO(1); MFMA_Q(4, 2, fa1, fb1); PRIO(0); BAR();
        // P8: kt1.Q3 ; stage buf1.B1(kb) ; counted wait
        STAGE_B(1, 1, offB_kb);
        VMW(4);
        BAR(); PRIO(1); MFMA_Q(4, 0, fa1, fb0); PRIO(0); BAR();
    }

    // ---- epilogue: kt=34 (buf0), kt=35 (buf1) ----
    {
        const int offA_35 = 8*65536 + 3*64;   // tap 8, ci0 192
        // eP1
        READ_A(fa0, 0, 0); READ_B(fb0, 0, 0);
        STAGE_A(1, 0, offA_35);
        BAR(); LGKM0(); PRIO(1); MFMA_Q(0, 0, fa0, fb0); PRIO(0); BAR();
        // eP2
        READ_B(fb1, 0, 2);
        STAGE_A(1, 1, offA_35);
        BAR(); LGKM0(); PRIO(1); MFMA_Q(0, 2, fa0, fb1); PRIO(0); BAR();
        // eP3
        READ_A(fa1, 0, 4);
        BAR(); LGKM0(); PRIO(1); MFMA_Q(4, 2, fa1, fb1); PRIO(0); BAR();
        // eP4: drain everything for kt=35
        VMW(0);
        BAR(); PRIO(1); MFMA_Q(4, 0, fa1, fb0); PRIO(0); BAR();
        // eP5..eP8: pure compute on buf1
        READ_A(fa0, 1, 0); READ_B(fb0, 1, 0);
        LGKM0(); PRIO(1); MFMA_Q(0, 0, fa0, fb0); PRIO(0);
        READ_B(fb1, 1, 2);
        LGKM0(); PRIO(1); MFMA_Q(0, 2, fa0, fb1); PRIO(0);
        READ_A(fa1, 1, 4);
        LGKM0(); PRIO(1); MFMA_Q(4, 2, fa1, fb1); MFMA_Q(4, 0, fa1, fb0); PRIO(0);
    }

    // ---- epilogue C-write ----
    const int row4 = (lane >> 4) * 4;
    #pragma unroll
    for (int nn = 0; nn < 4; ++nn) {
        const int n  = n0 + wn * 64 + nn * 16 + l15;
        const int r2 = n % 784;
        const int bt = n / 784;
        const int b = bt >> 4, t = bt & 15;
        #pragma unroll
        for (int m = 0; m < 8; ++m) {
            const int co = wr * 128 + m * 16 + row4;
            float* o = out + (((size_t)(b * 256 + co) * 16 + t) * 784) + r2;
            f32x4 v = acc[m][nn];
            o[0]         = v[0];
            o[12544]     = v[1];
            o[2 * 12544] = v[2];
            o[3 * 12544] = v[3];
        }
    }
}

// ---------------------------------------------------------------------------
extern "C" void kernel_launch(void* const* d_in, const int* in_sizes, int n_in,
                              void* d_out, int out_size, void* d_ws, size_t ws_size,
                              hipStream_t stream) {
    const float* x      = (const float*)d_in[0];
    const float* alpha  = (const float*)d_in[1];
    const float* weight = (const float*)d_in[2];
    float* out = (float*)d_out;

    unsigned short* xm = (unsigned short*)d_ws;
    unsigned short* wB = (unsigned short*)((char*)d_ws + XM_BYTES);

    modulate_kernel<<<dim3(NB * NT * HP), dim3(256), 0, stream>>>(x, alpha, xm);
    repack_w_kernel<<<dim3(9 * 256), dim3(256), 0, stream>>>(weight, wB);
    conv_gemm_kernel<<<dim3(392), dim3(512), 0, stream>>>(xm, wB, out);
}

// Round 3
// 162.535 us; speedup vs baseline: 1.2835x; 1.0559x over previous
//
#include <hip/hip_runtime.h>
#include <hip/hip_bf16.h>
#include <cstdint>

// Problem constants
#define CIN   256
#define COUT  256
#define NB    8
#define NT    16
#define NH    28
#define NW    28
#define HP    30
#define WP    30

#define XM_ELEMS   ((size_t)NB * NT * HP * WP * CIN)   // 29,491,200 bf16
#define XM_BYTES   (XM_ELEMS * 2)

typedef __bf16 bf16x8 __attribute__((ext_vector_type(8)));
typedef float  f32x4  __attribute__((ext_vector_type(4)));

#define AS1 __attribute__((address_space(1)))
#define AS3 __attribute__((address_space(3)))

static __device__ __forceinline__ unsigned short f2bf(float f) {
    __hip_bfloat16 h = __float2bfloat16(f);
    return __builtin_bit_cast(unsigned short, h);
}

// ---------------------------------------------------------------------------
// Pass 1: xm[b][t][hp][wp][ci] = bf16(x[b][ci][t][h][w] * alpha[b][ci][t])
// ---------------------------------------------------------------------------
__global__ void modulate_kernel(const float* __restrict__ x,
                                const float* __restrict__ alpha,
                                unsigned short* __restrict__ xm) {
    const int ci = threadIdx.x;
    const int blk = blockIdx.x;
    const int hp = blk % 30;
    const int bt = blk / 30;
    unsigned short* row = xm + (size_t)(bt * 900 + hp * 30) * 256;
    if (hp == 0 || hp == 29) {
        #pragma unroll
        for (int wp = 0; wp < 30; ++wp) row[wp * 256 + ci] = 0;
        return;
    }
    const int t = bt & 15, b = bt >> 4;
    const int h = hp - 1;
    const float a = alpha[(b * CIN + ci) * NT + t];
    const float* xrow = x + ((size_t)((b * CIN + ci) * NT + t) * NH + h) * NW;
    row[ci] = 0;
    row[29 * 256 + ci] = 0;
    const float4* xv = (const float4*)xrow;
    #pragma unroll
    for (int q = 0; q < 7; ++q) {
        float4 v = xv[q];
        row[(q * 4 + 1) * 256 + ci] = f2bf(v.x * a);
        row[(q * 4 + 2) * 256 + ci] = f2bf(v.y * a);
        row[(q * 4 + 3) * 256 + ci] = f2bf(v.z * a);
        row[(q * 4 + 4) * 256 + ci] = f2bf(v.w * a);
    }
}

// ---------------------------------------------------------------------------
// Pass 2: wB[tap][co][ci] = bf16(weight[co][ci][tap])
// ---------------------------------------------------------------------------
__global__ void repack_w_kernel(const float* __restrict__ w,
                                unsigned short* __restrict__ wB) {
    const int ci = threadIdx.x;
    const int tap = blockIdx.x >> 8;
    const int co  = blockIdx.x & 255;
    wB[((tap * 256 + co) * 256) + ci] = f2bf(w[(co * 256 + ci) * 9 + tap]);
}

// ---------------------------------------------------------------------------
// Pass 3: 256(co) x 224(n) implicit GEMM, 4-phase schedule, counted vmcnt.
// K=2304 = 36 tiles of BK=64 (tap-major). 8 waves (4M x 2N): per wave
// 64(co) x 112(n) = 4x7 fragments. LDS 128KB = 2 dbuf x (A 32KB + B 32KB
// [B padded to 256 rows]), XOR-swizzled. grid = 448 (2 exact CU rounds),
// block = 512. Swapped MFMA operands -> D rows = n -> f32x4 C-stores.
// ---------------------------------------------------------------------------

// stage one region (256 rows x 64k): 4 calls, each 8 waves x 8 rows
#define STAGE_A4(buf, off) do {                                               \
    _Pragma("unroll") for (int c_ = 0; c_ < 4; ++c_)                          \
        __builtin_amdgcn_global_load_lds(                                     \
            (const AS1 void*)(aSrc + (off) + c_ * 16384),                     \
            (AS3 void*)(lds + (buf)*32768 + c_*4096 + wave*512 + lane*8),     \
            16, 0, 0);                                                        \
} while (0)

#define STAGE_B4(buf, off) do {                                               \
    __builtin_amdgcn_global_load_lds((const AS1 void*)(bP0 + (off)),          \
        (AS3 void*)(lds + (buf)*32768 + 16384 + 0*4096 + wave*512 + lane*8), 16, 0, 0); \
    __builtin_amdgcn_global_load_lds((const AS1 void*)(bP1 + (off)),          \
        (AS3 void*)(lds + (buf)*32768 + 16384 + 1*4096 + wave*512 + lane*8), 16, 0, 0); \
    __builtin_amdgcn_global_load_lds((const AS1 void*)(bP2 + (off)),          \
        (AS3 void*)(lds + (buf)*32768 + 16384 + 2*4096 + wave*512 + lane*8), 16, 0, 0); \
    __builtin_amdgcn_global_load_lds((const AS1 void*)(bP3 + (off)),          \
        (AS3 void*)(lds + (buf)*32768 + 16384 + 3*4096 + wave*512 + lane*8), 16, 0, 0); \
} while (0)

#define READ_FA(buf) do {                                                     \
    _Pragma("unroll") for (int m_ = 0; m_ < 4; ++m_)                          \
    _Pragma("unroll") for (int kk_ = 0; kk_ < 2; ++kk_)                       \
        fa[m_][kk_] = *(const bf16x8*)(ldsc + (buf)*65536 +                   \
            (wm*64 + m_*16 + l15)*128 + (frag_sw ^ (kk_<<6)));                \
} while (0)

// fb slots 0..3 <- n-frags (base)..(base+3)
#define READ_FB4(buf, base) do {                                              \
    _Pragma("unroll") for (int f_ = 0; f_ < 4; ++f_)                          \
    _Pragma("unroll") for (int kk_ = 0; kk_ < 2; ++kk_)                       \
        fb[f_][kk_] = *(const bf16x8*)(ldsc + (buf)*65536 + 32768 +           \
            (wn*112 + ((base)+f_)*16 + l15)*128 + (frag_sw ^ (kk_<<6)));      \
} while (0)

#define READ_FB3(buf, base) do {                                              \
    _Pragma("unroll") for (int f_ = 0; f_ < 3; ++f_)                          \
    _Pragma("unroll") for (int kk_ = 0; kk_ < 2; ++kk_)                       \
        fb[f_][kk_] = *(const bf16x8*)(ldsc + (buf)*65536 + 32768 +           \
            (wn*112 + ((base)+f_)*16 + l15)*128 + (frag_sw ^ (kk_<<6)));      \
} while (0)

// swapped operands: D rows = n (fb free-dim), cols = co (fa free-dim)
#define MFMA_A() do {                                                         \
    _Pragma("unroll") for (int m_ = 0; m_ < 4; ++m_)                          \
    _Pragma("unroll") for (int f_ = 0; f_ < 4; ++f_)                          \
    _Pragma("unroll") for (int kk_ = 0; kk_ < 2; ++kk_)                       \
        acc[m_][f_] = __builtin_amdgcn_mfma_f32_16x16x32_bf16(                \
            fb[f_][kk_], fa[m_][kk_], acc[m_][f_], 0, 0, 0);                  \
} while (0)

#define MFMA_B() do {                                                         \
    _Pragma("unroll") for (int m_ = 0; m_ < 4; ++m_)                          \
    _Pragma("unroll") for (int f_ = 0; f_ < 3; ++f_)                          \
    _Pragma("unroll") for (int kk_ = 0; kk_ < 2; ++kk_)                       \
        acc[m_][4+f_] = __builtin_amdgcn_mfma_f32_16x16x32_bf16(              \
            fb[f_][kk_], fa[m_][kk_], acc[m_][4+f_], 0, 0, 0);                \
} while (0)

#define BAR()   __builtin_amdgcn_s_barrier()
#define LGKM0() asm volatile("s_waitcnt lgkmcnt(0)")
#define VMW(N)  asm volatile("s_waitcnt vmcnt(" #N ")" ::: "memory")
#define PRIO(x) __builtin_amdgcn_s_setprio(x)

#define OFFA(kt) (((kt) >> 2) * 65536 + ((kt) & 3) * 64)
#define OFFB(kt) (((((kt) >> 2) / 3) - 1) * 7680 + ((((kt) >> 2) % 3) - 1) * 256 + ((kt) & 3) * 64)

__global__ __launch_bounds__(512, 2) void conv_gemm_kernel(
    const unsigned short* __restrict__ xm,
    const unsigned short* __restrict__ wB,
    float* __restrict__ out) {
    __shared__ unsigned short lds[65536];   // 128 KB

    const int tid  = threadIdx.x;
    const int wave = tid >> 6;
    const int lane = tid & 63;
    const int n0   = blockIdx.x * 224;
    const int wm   = wave >> 1;            // 0..3 M-quarter (64 co)
    const int wn   = wave & 1;             // 0..1 N-half (112 n)
    const int l15  = lane & 15;

    // ---- staging sources (pre-swizzled k offset) ----
    const int swz8 = 8 * ((lane & 7) ^ (lane >> 3));
    const unsigned short* aSrc = wB + (wave * 8 + (lane >> 3)) * 256 + swz8;

    auto bcent = [&](int rowl) -> const unsigned short* {
        int r = rowl > 223 ? 223 : rowl;           // pad rows clamp
        int n = n0 + r;
        int w_ = n % 28, h_ = (n / 28) % 28, bt = n / 784;
        return xm + (size_t)((bt * 30 + h_ + 1) * 30 + (w_ + 1)) * 256 + swz8;
    };
    const unsigned short* bP0 = bcent(0 * 64 + wave * 8 + (lane >> 3));
    const unsigned short* bP1 = bcent(1 * 64 + wave * 8 + (lane >> 3));
    const unsigned short* bP2 = bcent(2 * 64 + wave * 8 + (lane >> 3));
    const unsigned short* bP3 = bcent(3 * 64 + wave * 8 + (lane >> 3));

    // ---- fragment read bases ----
    const char* ldsc = (const char*)lds;
    const int frag_sw = ((lane >> 4) * 16) ^ ((lane & 7) << 4);

    f32x4 acc[4][7];
    #pragma unroll
    for (int i = 0; i < 4; ++i)
        #pragma unroll
        for (int j = 0; j < 7; ++j) acc[i][j] = f32x4{0.f,0.f,0.f,0.f};

    bf16x8 fa[4][2], fb[4][2];

    // ---- prologue: b0A<-A(0), b0B<-B(0), b1A<-A(1) ----
    STAGE_A4(0, 0);
    STAGE_B4(0, OFFB(0));
    STAGE_A4(1, OFFA(1));
    VMW(4);
    BAR();

    #pragma unroll 1
    for (int it = 0; it < 17; ++it) {
        const int kt1 = 2 * it + 1;
        const int ka  = 2 * it + 2;
        const int kb  = 2 * it + 3;
        const int offB_k1 = OFFB(kt1);
        const int offA_ka = OFFA(ka);
        const int offB_ka = OFFB(ka);
        const int offA_kb = OFFA(kb);

        // P1: compute kt0 frags(fa, fb0-3) ; stage b1B <- B(kt1)
        READ_FA(0); READ_FB4(0, 0);
        STAGE_B4(1, offB_k1);
        BAR(); LGKM0(); PRIO(1); MFMA_A(); PRIO(0); BAR();
        // P2: kt0 frags 4-6 ; stage b0A <- A(ka) ; counted wait (b1 ready)
        READ_FB3(0, 4);
        STAGE_A4(0, offA_ka);
        VMW(4);
        BAR(); LGKM0(); PRIO(1); MFMA_B(); PRIO(0); BAR();
        // P3: kt1 frags(fa, fb0-3) ; stage b0B <- B(ka)
        READ_FA(1); READ_FB4(1, 0);
        STAGE_B4(0, offB_ka);
        BAR(); LGKM0(); PRIO(1); MFMA_A(); PRIO(0); BAR();
        // P4: kt1 frags 4-6 ; stage b1A <- A(kb) ; counted wait (b0 ready)
        READ_FB3(1, 4);
        STAGE_A4(1, offA_kb);
        VMW(4);
        BAR(); LGKM0(); PRIO(1); MFMA_B(); PRIO(0); BAR();
    }

    // ---- epilogue: kt=34 (buf0), kt=35 (buf1) ----
    {
        // eP1: stage b1B <- B(35)
        READ_FA(0); READ_FB4(0, 0);
        STAGE_B4(1, OFFB(35));
        BAR(); LGKM0(); PRIO(1); MFMA_A(); PRIO(0); BAR();
        // eP2: full drain (b1A from it=16 P4 + b1B from eP1)
        READ_FB3(0, 4);
        VMW(0);
        BAR(); LGKM0(); PRIO(1); MFMA_B(); PRIO(0); BAR();
        // eP3/eP4: pure compute on buf1
        READ_FA(1); READ_FB4(1, 0);
        LGKM0(); PRIO(1); MFMA_A(); PRIO(0);
        READ_FB3(1, 4);
        LGKM0(); PRIO(1); MFMA_B(); PRIO(0);
    }

    // ---- C-write: lane holds 4 consecutive n (rows) at one co (col) ----
    #pragma unroll
    for (int f = 0; f < 7; ++f) {
        const int n  = n0 + wn * 112 + f * 16 + ((lane >> 4) << 2);
        const int bt = n / 784;
        const int hw = n - bt * 784;
        const int b = bt >> 4, t = bt & 15;
        float* obase = out + ((size_t)(b * 256) * 16 + t) * 784 + hw;
        #pragma unroll
        for (int m = 0; m < 4; ++m) {
            const int co = wm * 64 + m * 16 + l15;
            *(f32x4*)(obase + (size_t)co * 12544) = acc[m][f];
        }
    }
}

// ---------------------------------------------------------------------------
extern "C" void kernel_launch(void* const* d_in, const int* in_sizes, int n_in,
                              void* d_out, int out_size, void* d_ws, size_t ws_size,
                              hipStream_t stream) {
    const float* x      = (const float*)d_in[0];
    const float* alpha  = (const float*)d_in[1];
    const float* weight = (const float*)d_in[2];
    float* out = (float*)d_out;

    unsigned short* xm = (unsigned short*)d_ws;
    unsigned short* wB = (unsigned short*)((char*)d_ws + XM_BYTES);

    modulate_kernel<<<dim3(NB * NT * HP), dim3(256), 0, stream>>>(x, alpha, xm);
    repack_w_kernel<<<dim3(9 * 256), dim3(256), 0, stream>>>(weight, wB);
    conv_gemm_kernel<<<dim3(448), dim3(512), 0, stream>>>(xm, wB, out);
}